// Round 6
// baseline (182.297 us; speedup 1.0000x reference)
//
#include <hip/hip_runtime.h>

#define BB 16
#define CC 80
#define DD 1024
#define HW 196
#define NSP (BB * HW)        // 3136 = 49 full waves, zero lane waste
#define NCH 8                // d-chunks of 128
#define DCH 128
#define CPB 4                // classes per scores block
#define NCQ (CC / CPB)       // 20 class-groups -> grid 2080 blocks
#define PCC 40               // classes per pool block
#define TWO_LOG2E 2.8853900817779268f

// ---------------- K1: scores (R0-proven, bitwise-identical) + imgT -----------
__global__ __launch_bounds__(256) void scores_k(const float* __restrict__ img,
                                                const float* __restrict__ word,
                                                const float* __restrict__ fa,
                                                float* __restrict__ partial,
                                                float* __restrict__ imgT) {
    const int g = blockIdx.x * 256 + threadIdx.x;
    if (g >= NSP) return;                           // wave-uniform exit
    const int b  = g / HW;
    const int hw = g - b * HW;
    const int d0 = blockIdx.y * DCH;
    const int c0 = blockIdx.z * CPB;

    const float* ip = img + ((size_t)b * DD + d0) * HW + hw;

    float p[CPB];
#pragma unroll
    for (int k = 0; k < CPB; ++k) p[k] = 0.f;

    for (int q = 0; q < DCH / 32; ++q) {            // 4 quarters of 32 d
        float iv[32];
        const float* qp = ip + (size_t)q * 32 * HW;
#pragma unroll
        for (int i = 0; i < 32; ++i)
            iv[i] = qp[(size_t)i * HW];

        if (blockIdx.z == 0) {                       // block-uniform branch
            float4* tp = (float4*)(imgT + (size_t)g * DD + d0 + q * 32);
#pragma unroll
            for (int i = 0; i < 8; ++i)
                tp[i] = make_float4(iv[4 * i], iv[4 * i + 1], iv[4 * i + 2], iv[4 * i + 3]);
        }

#pragma unroll
        for (int i = 0; i < 32; ++i)
            iv[i] *= TWO_LOG2E;                      // exp2(iv*w) == e^{2x}

        const float* fp = fa + d0 + q * 32;          // uniform -> SGPRs
#pragma unroll
        for (int k = 0; k < CPB; ++k) {
            const float* wp = word + (size_t)(c0 + k) * DD + d0 + q * 32;
            float p0 = 0.f, p1 = 0.f;
#pragma unroll
            for (int i = 0; i < 32; i += 2) {
                float y0 = iv[i]     * wp[i];
                float y1 = iv[i + 1] * wp[i + 1];
                float e0 = __builtin_amdgcn_exp2f(y0);
                float e1 = __builtin_amdgcn_exp2f(y1);
                float r0 = __builtin_amdgcn_rcpf(e0 + 1.f);
                float r1 = __builtin_amdgcn_rcpf(e1 + 1.f);
                p0 = fmaf(fp[i],     r0, p0);
                p1 = fmaf(fp[i + 1], r1, p1);
            }
            p[k] += p0 + p1;
        }
    }

#pragma unroll
    for (int k = 0; k < CPB; ++k)
        partial[(((size_t)b * NCH + blockIdx.y) * CC + (c0 + k)) * HW + hw]
            = (-TWO_LOG2E) * p[k];
}

// ---------------- K_sm: softmax, coef written IN-PLACE into partial[ch=0] ----
// One wave per (b,c); 320 blocks. Wave (b,c) is the only toucher of
// partial[b][*][c][*] and reads ch=0 before overwriting it -> race-free,
// zero extra workspace. Math bitwise-identical to the proven fused Phase-S.
__global__ __launch_bounds__(256) void softmax_k(float* partial) {
    const int idx = blockIdx.x * 4 + (threadIdx.x >> 6);   // b*CC + c
    const int l   = threadIdx.x & 63;
    const int b   = idx / CC;
    const int c   = idx - b * CC;

    float x0 = 0.f, x1 = 0.f, x2 = 0.f, x3 = 0.f;
#pragma unroll
    for (int ch = 0; ch < NCH; ++ch) {
        const float* pp = partial + (((size_t)b * NCH + ch) * CC + c) * HW;
        x0 += pp[l];
        x1 += pp[l + 64];
        x2 += pp[l + 128];
        if (l < HW - 192) x3 += pp[l + 192];
    }
    float x3m = (l < HW - 192) ? x3 : -3.4e38f;

    float m = fmaxf(fmaxf(x0, x1), fmaxf(x2, x3m));
#pragma unroll
    for (int off = 32; off >= 1; off >>= 1) m = fmaxf(m, __shfl_xor(m, off, 64));

    float e0 = __builtin_amdgcn_exp2f(x0 - m);
    float e1 = __builtin_amdgcn_exp2f(x1 - m);
    float e2 = __builtin_amdgcn_exp2f(x2 - m);
    float e3 = (l < HW - 192) ? __builtin_amdgcn_exp2f(x3 - m) : 0.f;

    float s = (e0 + e1) + (e2 + e3);
#pragma unroll
    for (int off = 32; off >= 1; off >>= 1) s += __shfl_xor(s, off, 64);

    float inv = __builtin_amdgcn_rcpf(s);
    float* cr = partial + (((size_t)b * NCH) * CC + c) * HW;   // ch=0 slice
    cr[l]       = e0 * inv;
    cr[l + 64]  = e1 * inv;
    cr[l + 128] = e2 * inv;
    if (l < HW - 192) cr[l + 192] = e3 * inv;
}

// ---------------- K2: pooling with imgT read ONCE-per-half -------------------
// Grid (16 b, 4 d-tiles of 256, 2 class-halves of 40) = 128 blocks x 256 thr.
// coef for 40 classes staged once into 32 KB LDS; imgT total read = 25.7 MB
// (was 256 MB in pool2's 20x class-group re-read). Phase P is software-
// pipelined 8 deep: 8 independent global b32 loads in flight while the
// previous 8 h-steps' 80 broadcast ds_read_b128 + 320 FMA retire.
// Prefetch overreads <=4 rows past imgT for b=15: workspace is ordered
// imgT-first so the overread lands inside partial (in-bounds, unused).
__global__ __launch_bounds__(256) void pool5_k(const float* __restrict__ imgT,
                                               const float* __restrict__ coef,
                                               float* __restrict__ out) {
    __shared__ float ct[PCC][200];                // 32000 B, padded rows
    const int b   = blockIdx.x;
    const int dt0 = blockIdx.y * 256;
    const int c0  = blockIdx.z * PCC;
    const int t   = threadIdx.x;

    // ---- stage coef[b][c0..c0+39][0..195] -> LDS (1960 float4, 16B-aligned)
    const float* cbase = coef + ((size_t)b * NCH * CC + c0) * HW;
#pragma unroll
    for (int i = 0; i < 8; ++i) {
        int idx = t + i * 256;                    // float4 index
        if (idx < (PCC * HW) / 4) {
            int c = idx / (HW / 4);               // 49 float4 per class
            int r = (idx - c * (HW / 4)) * 4;
            *(float4*)&ct[c][r] = *(const float4*)(cbase + (size_t)idx * 4);
        }
    }
    __syncthreads();

    // ---- Phase P: thread owns d = dt0 + t ----
    const float* ib = imgT + (size_t)b * HW * DD + dt0 + t;

    float acc[PCC];
#pragma unroll
    for (int k = 0; k < PCC; ++k) acc[k] = 0.f;

    float iv[8];
#pragma unroll
    for (int j = 0; j < 8; ++j) iv[j] = ib[(size_t)j * DD];

    for (int h = 0; h < 192; h += 8) {
        float nv[8];
#pragma unroll
        for (int j = 0; j < 8; ++j)               // h=184 prefetches rows 192..199
            nv[j] = ib[(size_t)(h + 8 + j) * DD]; // (<=4 rows past imgT: ws-safe)
#pragma unroll
        for (int k = 0; k < PCC; ++k) {
            float4 cA = *(const float4*)&ct[k][h];
            float4 cB = *(const float4*)&ct[k][h + 4];
            float a = acc[k];
            a = fmaf(cA.x, iv[0], a);
            a = fmaf(cA.y, iv[1], a);
            a = fmaf(cA.z, iv[2], a);
            a = fmaf(cA.w, iv[3], a);
            a = fmaf(cB.x, iv[4], a);
            a = fmaf(cB.y, iv[5], a);
            a = fmaf(cB.z, iv[6], a);
            a = fmaf(cB.w, iv[7], a);
            acc[k] = a;
        }
#pragma unroll
        for (int j = 0; j < 8; ++j) iv[j] = nv[j];
    }
    // tail h = 192..195 (iv[0..3] hold rows 192..195; iv[4..7] are garbage)
#pragma unroll
    for (int k = 0; k < PCC; ++k) {
        float4 cA = *(const float4*)&ct[k][192];
        float a = acc[k];
        a = fmaf(cA.x, iv[0], a);
        a = fmaf(cA.y, iv[1], a);
        a = fmaf(cA.z, iv[2], a);
        a = fmaf(cA.w, iv[3], a);
        acc[k] = a;
    }

    float* ob = out + ((size_t)b * CC + c0) * DD + dt0 + t;
#pragma unroll
    for (int k = 0; k < PCC; ++k)
        ob[(size_t)k * DD] = acc[k];
}

extern "C" void kernel_launch(void* const* d_in, const int* in_sizes, int n_in,
                              void* d_out, int out_size, void* d_ws, size_t ws_size,
                              hipStream_t stream) {
    // inputs: [0]=batch_size(int,1) [1]=img [2]=word [3]=fc_a_w [4]=fc_a_b
    const float* img  = (const float*)d_in[1];
    const float* word = (const float*)d_in[2];
    const float* fa   = (const float*)d_in[3];
    float* out = (float*)d_out;

    // workspace (floats), imgT FIRST so pool5's <=16KB prefetch overread past
    // imgT's end lands inside partial (in-bounds, values unused):
    //   imgT[3136][1024]        = 12.85 MB
    //   partial[16][8][80][196] =  8.03 MB   (20.88 MB total, proven footprint)
    float* imgT    = (float*)d_ws;
    float* partial = imgT + (size_t)NSP * DD;

    scores_k<<<dim3((NSP + 255) / 256, NCH, NCQ), 256, 0, stream>>>(img, word, fa, partial, imgT);
    softmax_k<<<dim3(BB * CC / 4), 256, 0, stream>>>(partial);
    pool5_k<<<dim3(BB, DD / 256, CC / PCC), 256, 0, stream>>>(imgT, partial, out);
}

// Round 7
// 159.277 us; speedup vs baseline: 1.1445x; 1.1445x over previous
//
#include <hip/hip_runtime.h>

#define BB 16
#define CC 80
#define DD 1024
#define HW 196
#define NSP (BB * HW)        // 3136 = 49 full waves, zero lane waste
#define NCH 8                // d-chunks of 128
#define DCH 128
#define CPB 4                // classes per scores block
#define NCQ (CC / CPB)       // 20 class-groups -> grid 2080 blocks
#define TWO_LOG2E 2.8853900817779268f

// ---------------- K1: scores (R0-proven, bitwise-identical) + imgT -----------
__global__ __launch_bounds__(256) void scores_k(const float* __restrict__ img,
                                                const float* __restrict__ word,
                                                const float* __restrict__ fa,
                                                float* __restrict__ partial,
                                                float* __restrict__ imgT) {
    const int g = blockIdx.x * 256 + threadIdx.x;
    if (g >= NSP) return;                           // wave-uniform exit
    const int b  = g / HW;
    const int hw = g - b * HW;
    const int d0 = blockIdx.y * DCH;
    const int c0 = blockIdx.z * CPB;

    const float* ip = img + ((size_t)b * DD + d0) * HW + hw;

    float p[CPB];
#pragma unroll
    for (int k = 0; k < CPB; ++k) p[k] = 0.f;

    for (int q = 0; q < DCH / 32; ++q) {            // 4 quarters of 32 d
        float iv[32];
        const float* qp = ip + (size_t)q * 32 * HW;
#pragma unroll
        for (int i = 0; i < 32; ++i)
            iv[i] = qp[(size_t)i * HW];

        if (blockIdx.z == 0) {                       // block-uniform branch
            float4* tp = (float4*)(imgT + (size_t)g * DD + d0 + q * 32);
#pragma unroll
            for (int i = 0; i < 8; ++i)
                tp[i] = make_float4(iv[4 * i], iv[4 * i + 1], iv[4 * i + 2], iv[4 * i + 3]);
        }

#pragma unroll
        for (int i = 0; i < 32; ++i)
            iv[i] *= TWO_LOG2E;                      // exp2(iv*w) == e^{2x}

        const float* fp = fa + d0 + q * 32;          // uniform -> SGPRs
#pragma unroll
        for (int k = 0; k < CPB; ++k) {
            const float* wp = word + (size_t)(c0 + k) * DD + d0 + q * 32;
            float p0 = 0.f, p1 = 0.f;
#pragma unroll
            for (int i = 0; i < 32; i += 2) {
                float y0 = iv[i]     * wp[i];
                float y1 = iv[i + 1] * wp[i + 1];
                float e0 = __builtin_amdgcn_exp2f(y0);
                float e1 = __builtin_amdgcn_exp2f(y1);
                float r0 = __builtin_amdgcn_rcpf(e0 + 1.f);
                float r1 = __builtin_amdgcn_rcpf(e1 + 1.f);
                p0 = fmaf(fp[i],     r0, p0);
                p1 = fmaf(fp[i + 1], r1, p1);
            }
            p[k] += p0 + p1;
        }
    }

#pragma unroll
    for (int k = 0; k < CPB; ++k)
        partial[(((size_t)b * NCH + blockIdx.y) * CC + (c0 + k)) * HW + hw]
            = (-TWO_LOG2E) * p[k];
}

// ---------------- K_sm: softmax, coef written IN-PLACE into partial[ch=0] ----
// One wave per (b,c); 320 blocks. Wave (b,c) is the only toucher of
// partial[b][*][c][*] and reads ch=0 before overwriting it -> race-free,
// zero extra workspace. Math bitwise-identical to the proven fused Phase-S.
__global__ __launch_bounds__(256) void softmax_k(float* partial) {
    const int idx = blockIdx.x * 4 + (threadIdx.x >> 6);   // b*CC + c
    const int l   = threadIdx.x & 63;
    const int b   = idx / CC;
    const int c   = idx - b * CC;

    float x0 = 0.f, x1 = 0.f, x2 = 0.f, x3 = 0.f;
#pragma unroll
    for (int ch = 0; ch < NCH; ++ch) {
        const float* pp = partial + (((size_t)b * NCH + ch) * CC + c) * HW;
        x0 += pp[l];
        x1 += pp[l + 64];
        x2 += pp[l + 128];
        if (l < HW - 192) x3 += pp[l + 192];
    }
    float x3m = (l < HW - 192) ? x3 : -3.4e38f;

    float m = fmaxf(fmaxf(x0, x1), fmaxf(x2, x3m));
#pragma unroll
    for (int off = 32; off >= 1; off >>= 1) m = fmaxf(m, __shfl_xor(m, off, 64));

    float e0 = __builtin_amdgcn_exp2f(x0 - m);
    float e1 = __builtin_amdgcn_exp2f(x1 - m);
    float e2 = __builtin_amdgcn_exp2f(x2 - m);
    float e3 = (l < HW - 192) ? __builtin_amdgcn_exp2f(x3 - m) : 0.f;

    float s = (e0 + e1) + (e2 + e3);
#pragma unroll
    for (int off = 32; off >= 1; off >>= 1) s += __shfl_xor(s, off, 64);

    float inv = __builtin_amdgcn_rcpf(s);
    float* cr = partial + (((size_t)b * NCH) * CC + c) * HW;   // ch=0 slice
    cr[l]       = e0 * inv;
    cr[l + 64]  = e1 * inv;
    cr[l + 128] = e2 * inv;
    if (l < HW - 192) cr[l + 192] = e3 * inv;
}

// ---------------- K2: register-tiled pooling (4c x 4d per thread) ------------
// Grid (16 b, 4 d-quads of 256, 5 c-chunks of 16) = 320 blocks x 256 thr
// (>=1.25 blocks/CU, 5 waves/CU). Wave w owns classes cq+4w..cq+4w+3; lane
// owns d = dq + 4*lane .. +3.  Per h: 1 coalesced global b128 (imgT row,
// 1 KB/wave) + 1 broadcast ds_read_b128 (coef quad, wave-uniform -> conflict-
// free) + 16 v_fma.  LDS pipe ~12 cyc/h/wave (vs pool5's 960), imgT L3
// traffic 64 MB (vs pool2's 257 MB), 16 independent acc chains.
__global__ __launch_bounds__(256) void pool6_k(const float* __restrict__ imgT,
                                               const float* __restrict__ coef,
                                               float* __restrict__ out) {
    __shared__ float ct[HW][16];                  // 12544 B, [h][c-local]
    const int b  = blockIdx.x;
    const int dq = blockIdx.y * 256;
    const int cq = blockIdx.z * 16;
    const int t  = threadIdx.x;

    // stage coef[b][cq..cq+15][*] transposed -> ct[h][c]; reads coalesced in h
    for (int idx = t; idx < 16 * HW; idx += 256) {
        const int c = idx / HW;
        const int h = idx - c * HW;
        ct[h][c] = coef[(((size_t)b * NCH) * CC + cq + c) * HW + h];
    }
    __syncthreads();

    const int cg = t >> 6;                        // wave -> class quad
    const int dg = t & 63;                        // lane -> d quad
    const float* ib = imgT + (size_t)b * HW * DD + dq + 4 * dg;
    const float* cp = &ct[0][4 * cg];

    float4 a0 = make_float4(0.f, 0.f, 0.f, 0.f);
    float4 a1 = make_float4(0.f, 0.f, 0.f, 0.f);
    float4 a2 = make_float4(0.f, 0.f, 0.f, 0.f);
    float4 a3 = make_float4(0.f, 0.f, 0.f, 0.f);

#pragma unroll 4
    for (int h = 0; h < HW; ++h) {
        const float4 iv = *(const float4*)(ib + (size_t)h * DD);
        const float4 cv = *(const float4*)(cp + h * 16);   // broadcast b128
        a0.x = fmaf(cv.x, iv.x, a0.x);
        a0.y = fmaf(cv.x, iv.y, a0.y);
        a0.z = fmaf(cv.x, iv.z, a0.z);
        a0.w = fmaf(cv.x, iv.w, a0.w);
        a1.x = fmaf(cv.y, iv.x, a1.x);
        a1.y = fmaf(cv.y, iv.y, a1.y);
        a1.z = fmaf(cv.y, iv.z, a1.z);
        a1.w = fmaf(cv.y, iv.w, a1.w);
        a2.x = fmaf(cv.z, iv.x, a2.x);
        a2.y = fmaf(cv.z, iv.y, a2.y);
        a2.z = fmaf(cv.z, iv.z, a2.z);
        a2.w = fmaf(cv.z, iv.w, a2.w);
        a3.x = fmaf(cv.w, iv.x, a3.x);
        a3.y = fmaf(cv.w, iv.y, a3.y);
        a3.z = fmaf(cv.w, iv.z, a3.z);
        a3.w = fmaf(cv.w, iv.w, a3.w);
    }

    float* ob = out + (((size_t)b * CC + cq + 4 * cg) * DD) + dq + 4 * dg;
    *(float4*)(ob)                  = a0;
    *(float4*)(ob + (size_t)DD)     = a1;
    *(float4*)(ob + (size_t)2 * DD) = a2;
    *(float4*)(ob + (size_t)3 * DD) = a3;
}

extern "C" void kernel_launch(void* const* d_in, const int* in_sizes, int n_in,
                              void* d_out, int out_size, void* d_ws, size_t ws_size,
                              hipStream_t stream) {
    // inputs: [0]=batch_size(int,1) [1]=img [2]=word [3]=fc_a_w [4]=fc_a_b
    const float* img  = (const float*)d_in[1];
    const float* word = (const float*)d_in[2];
    const float* fa   = (const float*)d_in[3];
    float* out = (float*)d_out;

    // workspace (floats): partial[16][8][80][196] = 8.03 MB
    //                   | imgT[3136][1024]        = 12.85 MB  (20.88 MB, proven)
    float* partial = (float*)d_ws;
    float* imgT    = partial + (size_t)BB * NCH * CC * HW;

    scores_k<<<dim3((NSP + 255) / 256, NCH, NCQ), 256, 0, stream>>>(img, word, fa, partial, imgT);
    softmax_k<<<dim3(BB * CC / 4), 256, 0, stream>>>(partial);
    pool6_k<<<dim3(BB, DD / 256, CC / 16), 256, 0, stream>>>(imgT, partial, out);
}

// Round 8
// 150.534 us; speedup vs baseline: 1.2110x; 1.0581x over previous
//
#include <hip/hip_runtime.h>

#define BB 16
#define CC 80
#define DD 1024
#define HW 196
#define NSP (BB * HW)        // 3136 = 49 full waves, zero lane waste
#define NCH 8                // d-chunks of 128
#define DCH 128
#define CPB 4                // classes per scores block
#define NCQ (CC / CPB)       // 20 class-groups -> grid 2080 blocks
#define TWO_LOG2E 2.8853900817779268f

// ---------------- K1: scores + imgT side-product -----------------------------
// R0 structure; ONE change: inner loop ILP 2 -> 4 independent chains.
// The y->exp2->(+1)->rcp->fma chain is ~24 cyc latency x 5 instrs; at
// ~2.4 waves/SIMD we need ~4 chains/wave to keep the trans pipe fed
// (measured: VALUBusy 64% at ILP=2, VALUBusy*dur invariant across R0/R3).
__global__ __launch_bounds__(256) void scores_k(const float* __restrict__ img,
                                                const float* __restrict__ word,
                                                const float* __restrict__ fa,
                                                float* __restrict__ partial,
                                                float* __restrict__ imgT) {
    const int g = blockIdx.x * 256 + threadIdx.x;
    if (g >= NSP) return;                           // wave-uniform exit
    const int b  = g / HW;
    const int hw = g - b * HW;
    const int d0 = blockIdx.y * DCH;
    const int c0 = blockIdx.z * CPB;

    const float* ip = img + ((size_t)b * DD + d0) * HW + hw;

    float p[CPB];
#pragma unroll
    for (int k = 0; k < CPB; ++k) p[k] = 0.f;

    for (int q = 0; q < DCH / 32; ++q) {            // 4 quarters of 32 d
        float iv[32];
        const float* qp = ip + (size_t)q * 32 * HW;
#pragma unroll
        for (int i = 0; i < 32; ++i)
            iv[i] = qp[(size_t)i * HW];

        if (blockIdx.z == 0) {                       // block-uniform branch
            float4* tp = (float4*)(imgT + (size_t)g * DD + d0 + q * 32);
#pragma unroll
            for (int i = 0; i < 8; ++i)
                tp[i] = make_float4(iv[4 * i], iv[4 * i + 1], iv[4 * i + 2], iv[4 * i + 3]);
        }

#pragma unroll
        for (int i = 0; i < 32; ++i)
            iv[i] *= TWO_LOG2E;                      // exp2(iv*w) == e^{2x}

        const float* fp = fa + d0 + q * 32;          // uniform -> SGPRs
#pragma unroll
        for (int k = 0; k < CPB; ++k) {
            const float* wp = word + (size_t)(c0 + k) * DD + d0 + q * 32;
            float p0 = 0.f, p1 = 0.f, p2 = 0.f, p3 = 0.f;
#pragma unroll
            for (int i = 0; i < 32; i += 4) {        // 4 independent chains
                float y0 = iv[i]     * wp[i];
                float y1 = iv[i + 1] * wp[i + 1];
                float y2 = iv[i + 2] * wp[i + 2];
                float y3 = iv[i + 3] * wp[i + 3];
                float e0 = __builtin_amdgcn_exp2f(y0);
                float e1 = __builtin_amdgcn_exp2f(y1);
                float e2 = __builtin_amdgcn_exp2f(y2);
                float e3 = __builtin_amdgcn_exp2f(y3);
                float r0 = __builtin_amdgcn_rcpf(e0 + 1.f);
                float r1 = __builtin_amdgcn_rcpf(e1 + 1.f);
                float r2 = __builtin_amdgcn_rcpf(e2 + 1.f);
                float r3 = __builtin_amdgcn_rcpf(e3 + 1.f);
                p0 = fmaf(fp[i],     r0, p0);
                p1 = fmaf(fp[i + 1], r1, p1);
                p2 = fmaf(fp[i + 2], r2, p2);
                p3 = fmaf(fp[i + 3], r3, p3);
            }
            p[k] += (p0 + p1) + (p2 + p3);
        }
    }

#pragma unroll
    for (int k = 0; k < CPB; ++k)
        partial[(((size_t)b * NCH + blockIdx.y) * CC + (c0 + k)) * HW + hw]
            = (-TWO_LOG2E) * p[k];
}

// ---------------- K2: fused softmax + pooling (R0-proven, bitwise-identical) -
__global__ __launch_bounds__(256) void pool2_k(const float* __restrict__ imgT,
                                               const float* __restrict__ partial,
                                               float* __restrict__ out) {
    __shared__ float ct[4 * HW];                  // 3136 B
    const int b   = blockIdx.x;
    const int dt0 = blockIdx.y * 256;
    const int cg  = blockIdx.z * 4;
    const int t   = threadIdx.x;
    const int w   = t >> 6, l = t & 63;

    // ---- Phase S: wave w -> softmax of class cg+w ----
    {
        const int c = cg + w;
        float x0 = 0.f, x1 = 0.f, x2 = 0.f, x3 = 0.f;
#pragma unroll
        for (int ch = 0; ch < NCH; ++ch) {
            const float* pp = partial + (((size_t)b * NCH + ch) * CC + c) * HW;
            x0 += pp[l];
            x1 += pp[l + 64];
            x2 += pp[l + 128];
            if (l < HW - 192) x3 += pp[l + 192];
        }
        float x3m = (l < HW - 192) ? x3 : -3.4e38f;

        float m = fmaxf(fmaxf(x0, x1), fmaxf(x2, x3m));
#pragma unroll
        for (int off = 32; off >= 1; off >>= 1) m = fmaxf(m, __shfl_xor(m, off, 64));

        float e0 = __builtin_amdgcn_exp2f(x0 - m);
        float e1 = __builtin_amdgcn_exp2f(x1 - m);
        float e2 = __builtin_amdgcn_exp2f(x2 - m);
        float e3 = (l < HW - 192) ? __builtin_amdgcn_exp2f(x3 - m) : 0.f;

        float s = (e0 + e1) + (e2 + e3);
#pragma unroll
        for (int off = 32; off >= 1; off >>= 1) s += __shfl_xor(s, off, 64);

        float inv = __builtin_amdgcn_rcpf(s);
        float* cr = ct + w * HW;
        cr[l]       = e0 * inv;
        cr[l + 64]  = e1 * inv;
        cr[l + 128] = e2 * inv;
        if (l < HW - 192) cr[l + 192] = e3 * inv;
    }
    __syncthreads();

    // ---- Phase P: thread owns d = dt0 + t ----
    const float* ib = imgT + (size_t)b * HW * DD + dt0 + t;

    float a0 = 0.f, a1 = 0.f, a2 = 0.f, a3 = 0.f;
#pragma unroll 7
    for (int h = 0; h < HW; h += 4) {
        float i0 = ib[(size_t)(h    ) * DD];
        float i1 = ib[(size_t)(h + 1) * DD];
        float i2 = ib[(size_t)(h + 2) * DD];
        float i3 = ib[(size_t)(h + 3) * DD];
        float4 c0v = *(const float4*)(ct + h);            // broadcast b128
        float4 c1v = *(const float4*)(ct + HW + h);
        float4 c2v = *(const float4*)(ct + 2 * HW + h);
        float4 c3v = *(const float4*)(ct + 3 * HW + h);
        a0 = fmaf(c0v.x, i0, fmaf(c0v.y, i1, fmaf(c0v.z, i2, fmaf(c0v.w, i3, a0))));
        a1 = fmaf(c1v.x, i0, fmaf(c1v.y, i1, fmaf(c1v.z, i2, fmaf(c1v.w, i3, a1))));
        a2 = fmaf(c2v.x, i0, fmaf(c2v.y, i1, fmaf(c2v.z, i2, fmaf(c2v.w, i3, a2))));
        a3 = fmaf(c3v.x, i0, fmaf(c3v.y, i1, fmaf(c3v.z, i2, fmaf(c3v.w, i3, a3))));
    }

    float* ob = out + ((size_t)b * CC + cg) * DD + dt0 + t;
    ob[0]              = a0;
    ob[DD]             = a1;
    ob[2 * (size_t)DD] = a2;
    ob[3 * (size_t)DD] = a3;
}

extern "C" void kernel_launch(void* const* d_in, const int* in_sizes, int n_in,
                              void* d_out, int out_size, void* d_ws, size_t ws_size,
                              hipStream_t stream) {
    // inputs: [0]=batch_size(int,1) [1]=img [2]=word [3]=fc_a_w [4]=fc_a_b
    const float* img  = (const float*)d_in[1];
    const float* word = (const float*)d_in[2];
    const float* fa   = (const float*)d_in[3];
    float* out = (float*)d_out;

    // workspace (floats): partial[16][8][80][196] = 8.03 MB
    //                   | imgT[3136][1024]        = 12.85 MB  (20.88 MB, proven)
    float* partial = (float*)d_ws;
    float* imgT    = partial + (size_t)BB * NCH * CC * HW;

    scores_k<<<dim3((NSP + 255) / 256, NCH, NCQ), 256, 0, stream>>>(img, word, fa, partial, imgT);
    pool2_k<<<dim3(BB, DD / 256, CC / 4), 256, 0, stream>>>(imgT, partial, out);
}